// Round 1
// baseline (97.931 us; speedup 1.0000x reference)
//
#include <hip/hip_runtime.h>
#include <math.h>

// Problem constants (from reference)
#define NSAMP 16
#define NPTS  512
#define MDIM  4096     // 64*64 grid
#define NIT   100

// 16x16 window (rows rn-7..rn+8, cols cn-7..cn+8), 4 cells/lane for a wave.
// Support analysis (R4-R12-validated): first-visit pits (depth ~step1*khi ~
// 512) displace the softmax mode ~3 cells to the pit rim; rim + mass tail
// needs +-6 cells -> 16x16 is the minimum safe window. All 256 cells valid.
#define R0MAX 48

// No-max softmax safety (R12-validated): z = v - 0.1*d^2 < 0 always and
// S >= e^-28 -> unshifted __expf neither overflows nor underflows S.

// parity swizzle: odd rows XOR col by 16 -> ~2 lanes/bank (R7: 75k -> 2k).
__device__ __forceinline__ int swz(int r, int c) {
  return r * 64 + (c ^ ((r & 1) << 4));
}

// ---------------- Threefry-2x32 (JAX-exact, partitionable path; R0-verified)
__device__ __forceinline__ void tf2x32(unsigned k0, unsigned k1,
                                       unsigned c0, unsigned c1,
                                       unsigned &o0, unsigned &o1)
{
  unsigned ks2 = k0 ^ k1 ^ 0x1BD11BDAu;
  unsigned x0 = c0 + k0, x1 = c1 + k1;
#define ROT(r) x0 += x1; x1 = (x1 << (r)) | (x1 >> (32 - (r))); x1 ^= x0;
#define G0 ROT(13) ROT(15) ROT(26) ROT(6)
#define G1 ROT(17) ROT(29) ROT(16) ROT(24)
  G0 x0 += k1;  x1 += ks2 + 1u;
  G1 x0 += ks2; x1 += k0  + 2u;
  G0 x0 += k0;  x1 += k1  + 3u;
  G1 x0 += k1;  x1 += ks2 + 4u;
  G0 x0 += ks2; x1 += k0  + 5u;
#undef G0
#undef G1
#undef ROT
  o0 = x0; o1 = x1;
}

__device__ __forceinline__ int rand_idx(int f)
{
  unsigned ka, kb, w0, w1;
  tf2x32(0u, 1u, 0u, 1u, ka, kb);            // split(key(1))[1] — folded
  tf2x32(ka, kb, 0u, (unsigned)f, w0, w1);   // random_bits elem f
  return (int)((w0 ^ w1) & 511u);
}

// ---------------- wave64 sum via DPP (R1-R12-verified pattern) --------------
template<int CTRL>
__device__ __forceinline__ float dpp_mv(float v, float id)
{
  return __int_as_float(__builtin_amdgcn_update_dpp(
      __float_as_int(id), __float_as_int(v), CTRL, 0xF, 0xF, false));
}

__device__ __forceinline__ float waveSum(float v)
{
  v += dpp_mv<0x111>(v, 0.0f);
  v += dpp_mv<0x112>(v, 0.0f);
  v += dpp_mv<0x114>(v, 0.0f);
  v += dpp_mv<0x118>(v, 0.0f);
  v += dpp_mv<0x142>(v, 0.0f);
  v += dpp_mv<0x143>(v, 0.0f);
  return __int_as_float(__builtin_amdgcn_readlane(__float_as_int(v), 63));
}

// ---------------- Fused kernel: scan (wave 0) + rows (16 waves) -------------
// Phase 1 (R6-R12-validated algebra): v = 0.1*cur + lnb = D + b*A lazily;
// avacc = sum(Pk*khi), Pk = step1*(101-k)/100; beta = 10*(b*SP - avacc);
// w = 0.1*beta + lnb. loss: analytically 0 (R6-R12-validated).
// R14 = R13 + speculative next-window prefetch: the (D,av)/b state for
// window k+1 is read EARLY (end of iter k-1, i.e. before iter k's writes)
// and re-read after the writes ONLY when win_k and win_{k+1} intersect
// (|dr0|<16 && |dc0|<16, wave-uniform ints from cstB). ~2/3 of iterations
// are disjoint -> the ds_write->ds_read round-trip (~100 cy) leaves the
// critical chain. Values (and results) are bit-identical to R13.
__global__ __launch_bounds__(1024) void kern_fused(
    const float *__restrict__ normed, const float *__restrict__ pts,
    float *__restrict__ out)
{
  const int s = blockIdx.x;
  const int t = threadIdx.x;
  const int v = t >> 6;            // wave 0..15
  const int L = t & 63;

  __shared__ float2 dav[MDIM];     // 32 KB: (D, avacc), swizzled
  __shared__ float  barr[MDIM];    // 16 KB: b, becomes w[] after epilogue
  __shared__ float2 pts2[NPTS];    // 4 KB
  __shared__ float4 cstA[NIT + 4]; // (ux, uy, step1, Pk) per iter
  __shared__ int2   cstB[NIT + 4]; // (r0, c0) per iter
  __shared__ float  spfin;         // exact sum of Pk, k ascending
  __shared__ float  wdred[16], otred[16];

  // ---- init (all 16 waves; wave v owns grid rows 4v..4v+3) ----
  #pragma unroll
  for (int l = 0; l < 4; ++l) {
    const int r = 4 * v + l;
    const float bv = normed[s * MDIM + r * 64 + L];
    const int idx = swz(r, L);
    dav[idx]  = make_float2(__logf(bv), 0.0f);   // v0 = lnb
    barr[idx] = bv;
  }
  if (t < NPTS) pts2[t] = ((const float2 *)pts)[s * NPTS + t];
  // per-iteration constants (bit-identical formulas, hoisted; R8-validated)
  if (t < NIT + 4) {
    const int kk = t < NIT ? t : (NIT - 1);
    const int idx = rand_idx(s * NIT + kk);
    const float2 p = ((const float2 *)pts)[s * NPTS + idx];
    const int rn = (int)floorf((p.y - 4.0f) * 0.125f + 0.5f);
    const int cn = (int)floorf((p.x - 4.0f) * 0.125f + 0.5f);
    int r0 = rn - 7; r0 = r0 < 0 ? 0 : (r0 > R0MAX ? R0MAX : r0);
    int c0 = cn - 7; c0 = c0 < 0 ? 0 : (c0 > R0MAX ? R0MAX : c0);
    const float kf    = (float)(kk + 1);
    const float step1 = 512.0f * __builtin_amdgcn_rsqf(kf);   // 0.1*lr/sqrt(k)
    const float Pk    = step1 * (0.01f * (101.0f - kf));
    cstA[t] = make_float4(p.x - (float)(8 * c0 + 4),
                          p.y - (float)(8 * r0 + 4), step1, Pk);
    cstB[t] = make_int2(r0, c0);
  }
  __syncthreads();

  const int rbase = L >> 4;        // 0..3 (window row within quad)
  const int cbase = L & 15;        // window col
  const float fc8 = (float)(8 * cbase);
  const float fr8 = (float)(8 * rbase);

  // ---- phase 1: 100-iter ASGD scan, wave 0 only ----
  // (wave 1 lane 0 concurrently builds spfin with the identical add order —
  //  bit-exact vs R12's in-loop SP accumulation; R10-validated prefix trick)
  if (t == 64) {
    float SPa = 0.0f;
    for (int k = 0; k < NIT; ++k) SPa += cstA[k].w;
    spfin = SPa;
  }
  if (v == 0) {
    float A = 0.0f;
    // iter-0 state (fresh: no writes have happened yet)
    float4 cA = cstA[0];
    int2   cB = cstB[0];
    int j0 = swz(cB.x + rbase, cB.y + cbase);
    float2 c0v = dav[j0      ]; float b0v = barr[j0      ];
    float2 c1v = dav[j0 + 256]; float b1v = barr[j0 + 256];
    float2 c2v = dav[j0 + 512]; float b2v = barr[j0 + 512];
    float2 c3v = dav[j0 + 768]; float b3v = barr[j0 + 768];
    // iter-1 speculative prefetch (validated/refreshed inside the loop)
    float4 cAn = cstA[1];
    int2   cBn = cstB[1];
    int j1 = swz(cBn.x + rbase, cBn.y + cbase);
    float2 d0n = dav[j1      ]; float b0n = barr[j1      ];
    float2 d1n = dav[j1 + 256]; float b1n = barr[j1 + 256];
    float2 d2n = dav[j1 + 512]; float b2n = barr[j1 + 512];
    float2 d3n = dav[j1 + 768]; float b3n = barr[j1 + 768];

    for (int k = 0; k < NIT; ++k) {
      const float dx  = cA.x - fc8;       // x - (8*(c0+cbase)+4)
      const float dxx = dx * dx;
      const float ty  = cA.y - fr8;       // dy_q = ty - 32q
      // unshifted exp: z < 0 always (R12-validated) -> no max reduction
      const float e0 = __expf(fmaf(fmaf(ty,          ty,          dxx), -0.1f, fmaf(b0v, A, c0v.x)));
      const float e1 = __expf(fmaf(fmaf(ty - 32.0f, ty - 32.0f, dxx), -0.1f, fmaf(b1v, A, c1v.x)));
      const float e2 = __expf(fmaf(fmaf(ty - 64.0f, ty - 64.0f, dxx), -0.1f, fmaf(b2v, A, c2v.x)));
      const float e3 = __expf(fmaf(fmaf(ty - 96.0f, ty - 96.0f, dxx), -0.1f, fmaf(b3v, A, c3v.x)));

      const float S    = waveSum((e0 + e1) + (e2 + e3));   // > 0
      const float invS = __builtin_amdgcn_rcpf(S);
      const float cD = cA.z * invS, cAv = cA.w * invS;

      c0v.x = fmaf(-cD, e0, c0v.x); c0v.y = fmaf(cAv, e0, c0v.y);
      c1v.x = fmaf(-cD, e1, c1v.x); c1v.y = fmaf(cAv, e1, c1v.y);
      c2v.x = fmaf(-cD, e2, c2v.x); c2v.y = fmaf(cAv, e2, c2v.y);
      c3v.x = fmaf(-cD, e3, c3v.x); c3v.y = fmaf(cAv, e3, c3v.y);
      dav[j0      ] = c0v;
      dav[j0 + 256] = c1v;
      dav[j0 + 512] = c2v;
      dav[j0 + 768] = c3v;

      A += cA.z;

      // speculation check: windows intersect iff |dr0|<16 && |dc0|<16.
      // Wave-uniform (cstB values). Only then must the early prefetch be
      // refreshed to observe this iteration's writes (same-wave DS order
      // guarantees RAW for the re-read). b is read-only -> never re-read.
      const int dr = cB.x - cBn.x;
      const int dc = cB.y - cBn.y;
      if ((unsigned)(dr + 15) < 31u && (unsigned)(dc + 15) < 31u) {
        d0n = dav[j1      ];
        d1n = dav[j1 + 256];
        d2n = dav[j1 + 512];
        d3n = dav[j1 + 768];
      }

      // rotate next -> cur
      cA = cAn; cB = cBn; j0 = j1;
      c0v = d0n; c1v = d1n; c2v = d2n; c3v = d3n;
      b0v = b0n; b1v = b1n; b2v = b2n; b3v = b3n;

      // speculative prefetch for k+2 (issued after iter-k writes, so it is
      // fresh w.r.t. all iterations <= k; iter k+1's check covers the rest)
      cAn = cstA[k + 2];
      cBn = cstB[k + 2];
      j1 = swz(cBn.x + rbase, cBn.y + cbase);
      d0n = dav[j1      ]; b0n = barr[j1      ];
      d1n = dav[j1 + 256]; b1n = barr[j1 + 256];
      d2n = dav[j1 + 512]; b2n = barr[j1 + 512];
      d3n = dav[j1 + 768]; b3n = barr[j1 + 768];
    }
  }
  __syncthreads();                               // dav final; spfin ready

  // ---- epilogue (ALL 16 waves, own slab): barr <- w[]; ot partials ----
  {
    const float SP = spfin;
    float p_ot = 0.0f;
    #pragma unroll
    for (int l = 0; l < 4; ++l) {
      const int idx = swz(4 * v + l, L);
      const float2 cd = dav[idx];
      const float bb  = barr[idx];
      const float tt  = fmaf(bb, SP, -cd.y);     // 0.1*beta
      barr[idx] = tt + __logf(bb);               // w = 0.1*beta + lnb
      p_ot = fmaf(bb, 10.0f * tt, p_ot);
    }
    p_ot = waveSum(p_ot);
    if (L == 0) otred[v] = p_ot;
  }
  __syncthreads();                               // barr now holds w[]

  // ---- phase 2: windowed per-point wd, 4 points/pass interleaved (R12) ----
  float wdacc = 0.0f;
  for (int g = 0; g < 8; ++g) {
    float pe[4], pq[4];
    #pragma unroll
    for (int i = 0; i < 4; ++i) {
      const int p = 32 * v + 4 * g + i;
      const float2 pt = pts2[p];                 // LDS broadcast
      const float x = pt.x, y = pt.y;
      const int rn = (int)floorf((y - 4.0f) * 0.125f + 0.5f);
      const int cn = (int)floorf((x - 4.0f) * 0.125f + 0.5f);
      int r0 = rn - 7; r0 = r0 < 0 ? 0 : (r0 > R0MAX ? R0MAX : r0);
      int c0 = cn - 7; c0 = c0 < 0 ? 0 : (c0 > R0MAX ? R0MAX : c0);
      const int rl = r0 + rbase;
      const int cl = c0 + cbase;
      const int j0 = swz(rl, cl);

      const float dx  = x - (float)(8 * cl + 4);
      const float dxx = dx * dx;
      const float ty  = y - (float)(8 * rl + 4);
      float spe = 0.0f, spq = 0.0f;
      #pragma unroll
      for (int q = 0; q < 4; ++q) {
        const float wv = barr[j0 + 256 * q];
        const float dy = ty - (float)(32 * q);
        const float qq = fmaf(dy, dy, dxx);
        const float e  = __expf(fmaf(qq, -0.1f, wv));
        spe += e;
        spq = fmaf(e, qq, spq);
      }
      pe[i] = spe; pq[i] = spq;
    }
    // 8 interleaved DPP sum chains
    #pragma unroll
    for (int i = 0; i < 4; ++i) { pe[i] += dpp_mv<0x111>(pe[i], 0.0f); pq[i] += dpp_mv<0x111>(pq[i], 0.0f); }
    #pragma unroll
    for (int i = 0; i < 4; ++i) { pe[i] += dpp_mv<0x112>(pe[i], 0.0f); pq[i] += dpp_mv<0x112>(pq[i], 0.0f); }
    #pragma unroll
    for (int i = 0; i < 4; ++i) { pe[i] += dpp_mv<0x114>(pe[i], 0.0f); pq[i] += dpp_mv<0x114>(pq[i], 0.0f); }
    #pragma unroll
    for (int i = 0; i < 4; ++i) { pe[i] += dpp_mv<0x118>(pe[i], 0.0f); pq[i] += dpp_mv<0x118>(pq[i], 0.0f); }
    #pragma unroll
    for (int i = 0; i < 4; ++i) { pe[i] += dpp_mv<0x142>(pe[i], 0.0f); pq[i] += dpp_mv<0x142>(pq[i], 0.0f); }
    #pragma unroll
    for (int i = 0; i < 4; ++i) { pe[i] += dpp_mv<0x143>(pe[i], 0.0f); pq[i] += dpp_mv<0x143>(pq[i], 0.0f); }
    #pragma unroll
    for (int i = 0; i < 4; ++i) {
      const float PE = __int_as_float(__builtin_amdgcn_readlane(__float_as_int(pe[i]), 63));
      const float PQ = __int_as_float(__builtin_amdgcn_readlane(__float_as_int(pq[i]), 63));
      wdacc = fmaf(PQ, __builtin_amdgcn_rcpf(PE), wdacc);
    }
  }
  if (L == 0) wdred[v] = wdacc;
  __syncthreads();
  if (t == 0) {
    float wd = 0.0f, ot = 0.0f;
    #pragma unroll
    for (int i = 0; i < 16; ++i) { wd += wdred[i]; ot += otred[i]; }
    atomicAdd(&out[1], wd * (1.0f / 512.0f));
    atomicAdd(&out[2], ot);
    // out[0] (loss): analytically exact 0; memset provides it.
  }
}

extern "C" void kernel_launch(void* const* d_in, const int* in_sizes, int n_in,
                              void* d_out, int out_size, void* d_ws, size_t ws_size,
                              hipStream_t stream)
{
  (void)in_sizes; (void)n_in; (void)out_size; (void)d_ws; (void)ws_size;
  const float *normed = (const float *)d_in[0];
  const float *pts    = (const float *)d_in[2];
  float *out = (float *)d_out;

  hipMemsetAsync(out, 0, 3 * sizeof(float), stream);
  kern_fused<<<dim3(NSAMP), dim3(1024), 0, stream>>>(normed, pts, out);
}

// Round 2
// 96.563 us; speedup vs baseline: 1.0142x; 1.0142x over previous
//
#include <hip/hip_runtime.h>
#include <math.h>

// Problem constants (from reference)
#define NSAMP 16
#define NPTS  512
#define MDIM  4096     // 64*64 grid
#define NIT   100

// 16x16 window (rows rn-7..rn+8, cols cn-7..cn+8), 4 cells/lane for a wave.
// Support analysis (R4-R12-validated): first-visit pits (depth ~step1*khi ~
// 512) displace the softmax mode ~3 cells to the pit rim; rim + mass tail
// needs +-6 cells -> 16x16 is the minimum safe window. All 256 cells valid.
#define R0MAX 48

// No-max softmax safety (R12-validated): z = v - 0.1*d^2 < 0 always and
// S >= e^-28 -> unshifted __expf neither overflows nor underflows S.

// parity swizzle: odd rows XOR col by 16 -> ~2 lanes/bank (R7: 75k -> 2k).
__device__ __forceinline__ int swz(int r, int c) {
  return r * 64 + (c ^ ((r & 1) << 4));
}

// ---------------- Threefry-2x32 (JAX-exact, partitionable path; R0-verified)
__device__ __forceinline__ void tf2x32(unsigned k0, unsigned k1,
                                       unsigned c0, unsigned c1,
                                       unsigned &o0, unsigned &o1)
{
  unsigned ks2 = k0 ^ k1 ^ 0x1BD11BDAu;
  unsigned x0 = c0 + k0, x1 = c1 + k1;
#define ROT(r) x0 += x1; x1 = (x1 << (r)) | (x1 >> (32 - (r))); x1 ^= x0;
#define G0 ROT(13) ROT(15) ROT(26) ROT(6)
#define G1 ROT(17) ROT(29) ROT(16) ROT(24)
  G0 x0 += k1;  x1 += ks2 + 1u;
  G1 x0 += ks2; x1 += k0  + 2u;
  G0 x0 += k0;  x1 += k1  + 3u;
  G1 x0 += k1;  x1 += ks2 + 4u;
  G0 x0 += ks2; x1 += k0  + 5u;
#undef G0
#undef G1
#undef ROT
  o0 = x0; o1 = x1;
}

__device__ __forceinline__ int rand_idx(int f)
{
  unsigned ka, kb, w0, w1;
  tf2x32(0u, 1u, 0u, 1u, ka, kb);            // split(key(1))[1] — folded
  tf2x32(ka, kb, 0u, (unsigned)f, w0, w1);   // random_bits elem f
  return (int)((w0 ^ w1) & 511u);
}

// ---------------- wave64 sum via DPP (R1-R12-verified pattern) --------------
template<int CTRL>
__device__ __forceinline__ float dpp_mv(float v, float id)
{
  return __int_as_float(__builtin_amdgcn_update_dpp(
      __float_as_int(id), __float_as_int(v), CTRL, 0xF, 0xF, false));
}

__device__ __forceinline__ float waveSum(float v)
{
  v += dpp_mv<0x111>(v, 0.0f);
  v += dpp_mv<0x112>(v, 0.0f);
  v += dpp_mv<0x114>(v, 0.0f);
  v += dpp_mv<0x118>(v, 0.0f);
  v += dpp_mv<0x142>(v, 0.0f);
  v += dpp_mv<0x143>(v, 0.0f);
  return __int_as_float(__builtin_amdgcn_readlane(__float_as_int(v), 63));
}

// ---------------- Fused kernel: scan (wave 0) + rows (16 waves) -------------
// Phase 1 (R6-R12-validated algebra): v = 0.1*cur + lnb = D + b*A lazily;
// avacc = sum(Pk*khi), Pk = step1*(101-k)/100; beta = 10*(b*SP - avacc);
// w = 0.1*beta + lnb. loss: analytically 0 (R6-R12-validated).
//
// R15 speculation, corrected from R14's regression: ISSUE UNCONDITIONALLY,
// CONSUME CONDITIONALLY. The window-(k+1) re-read is always issued right
// after iter-k's writes (it is always *correct*: when windows are disjoint
// it returns bytes identical to the early speculative prefetch). A scalar-
// uniform branch (readfirstlane; asm-volatile arms defeat if-conversion so
// it stays a real s_cbranch, not v_cndmask) then selects WHICH registers to
// consume: taken (~1/3, windows intersect) waits a counted lgkmcnt for the
// re-read only; not-taken (~2/3) consumes the iteration-old prefetch with
// no wait -> the ds_write->ds_read round-trip leaves the critical chain.
// #pragma unroll 2 lets copy-prop delete the rotate movs (R14's fatal
// consume-at-issue was the rotate reading freshly issued loads).
// Values consumed are bit-identical in both paths -> results identical.
__global__ __launch_bounds__(1024) void kern_fused(
    const float *__restrict__ normed, const float *__restrict__ pts,
    float *__restrict__ out)
{
  const int s = blockIdx.x;
  const int t = threadIdx.x;
  const int v = t >> 6;            // wave 0..15
  const int L = t & 63;

  __shared__ float2 dav[MDIM];     // 32 KB: (D, avacc), swizzled
  __shared__ float  barr[MDIM];    // 16 KB: b, becomes w[] after epilogue
  __shared__ float2 pts2[NPTS];    // 4 KB
  __shared__ float4 cstA[NIT + 4]; // (ux, uy, step1, Pk) per iter
  __shared__ int2   cstB[NIT + 4]; // (r0, c0) per iter
  __shared__ float  spfin;         // exact sum of Pk, k ascending
  __shared__ float  wdred[16], otred[16];

  // ---- init (all 16 waves; wave v owns grid rows 4v..4v+3) ----
  #pragma unroll
  for (int l = 0; l < 4; ++l) {
    const int r = 4 * v + l;
    const float bv = normed[s * MDIM + r * 64 + L];
    const int idx = swz(r, L);
    dav[idx]  = make_float2(__logf(bv), 0.0f);   // v0 = lnb
    barr[idx] = bv;
  }
  if (t < NPTS) pts2[t] = ((const float2 *)pts)[s * NPTS + t];
  // per-iteration constants (bit-identical formulas, hoisted; R8-validated)
  if (t < NIT + 4) {
    const int kk = t < NIT ? t : (NIT - 1);
    const int idx = rand_idx(s * NIT + kk);
    const float2 p = ((const float2 *)pts)[s * NPTS + idx];
    const int rn = (int)floorf((p.y - 4.0f) * 0.125f + 0.5f);
    const int cn = (int)floorf((p.x - 4.0f) * 0.125f + 0.5f);
    int r0 = rn - 7; r0 = r0 < 0 ? 0 : (r0 > R0MAX ? R0MAX : r0);
    int c0 = cn - 7; c0 = c0 < 0 ? 0 : (c0 > R0MAX ? R0MAX : c0);
    const float kf    = (float)(kk + 1);
    const float step1 = 512.0f * __builtin_amdgcn_rsqf(kf);   // 0.1*lr/sqrt(k)
    const float Pk    = step1 * (0.01f * (101.0f - kf));
    cstA[t] = make_float4(p.x - (float)(8 * c0 + 4),
                          p.y - (float)(8 * r0 + 4), step1, Pk);
    cstB[t] = make_int2(r0, c0);
  }
  __syncthreads();

  const int rbase = L >> 4;        // 0..3 (window row within quad)
  const int cbase = L & 15;        // window col
  const float fc8 = (float)(8 * cbase);
  const float fr8 = (float)(8 * rbase);

  // ---- phase 1: 100-iter ASGD scan, wave 0 only ----
  // (wave 1 lane 0 concurrently builds spfin with the identical add order —
  //  bit-exact vs R12's in-loop SP accumulation; R10-validated prefix trick)
  if (t == 64) {
    float SPa = 0.0f;
    for (int k = 0; k < NIT; ++k) SPa += cstA[k].w;
    spfin = SPa;
  }
  if (v == 0) {
    float A = 0.0f;
    // iter-0 state (fresh: no writes have happened yet)
    float4 cA = cstA[0];
    int2   cB = cstB[0];
    int j0 = swz(cB.x + rbase, cB.y + cbase);
    float2 c0v = dav[j0      ]; float b0v = barr[j0      ];
    float2 c1v = dav[j0 + 256]; float b1v = barr[j0 + 256];
    float2 c2v = dav[j0 + 512]; float b2v = barr[j0 + 512];
    float2 c3v = dav[j0 + 768]; float b3v = barr[j0 + 768];
    // iter-1 speculative prefetch (selected against the re-read in-loop)
    float4 cAn = cstA[1];
    int2   cBn = cstB[1];
    int j1 = swz(cBn.x + rbase, cBn.y + cbase);
    float2 d0n = dav[j1      ]; float b0n = barr[j1      ];
    float2 d1n = dav[j1 + 256]; float b1n = barr[j1 + 256];
    float2 d2n = dav[j1 + 512]; float b2n = barr[j1 + 512];
    float2 d3n = dav[j1 + 768]; float b3n = barr[j1 + 768];

    #pragma unroll 2
    for (int k = 0; k < NIT; ++k) {
      // next-next constants read at the TOP: their wait (at j2 computation,
      // after writes+re-read are issued) stays a cheap counted lgkmcnt.
      const float4 cAnn = cstA[k + 2];
      const int2   cBnn = cstB[k + 2];

      const float dx  = cA.x - fc8;       // x - (8*(c0+cbase)+4)
      const float dxx = dx * dx;
      const float ty  = cA.y - fr8;       // dy_q = ty - 32q
      // unshifted exp: z < 0 always (R12-validated) -> no max reduction
      const float e0 = __expf(fmaf(fmaf(ty,          ty,          dxx), -0.1f, fmaf(b0v, A, c0v.x)));
      const float e1 = __expf(fmaf(fmaf(ty - 32.0f, ty - 32.0f, dxx), -0.1f, fmaf(b1v, A, c1v.x)));
      const float e2 = __expf(fmaf(fmaf(ty - 64.0f, ty - 64.0f, dxx), -0.1f, fmaf(b2v, A, c2v.x)));
      const float e3 = __expf(fmaf(fmaf(ty - 96.0f, ty - 96.0f, dxx), -0.1f, fmaf(b3v, A, c3v.x)));

      const float S    = waveSum((e0 + e1) + (e2 + e3));   // > 0
      const float invS = __builtin_amdgcn_rcpf(S);
      const float cD = cA.z * invS, cAv = cA.w * invS;

      c0v.x = fmaf(-cD, e0, c0v.x); c0v.y = fmaf(cAv, e0, c0v.y);
      c1v.x = fmaf(-cD, e1, c1v.x); c1v.y = fmaf(cAv, e1, c1v.y);
      c2v.x = fmaf(-cD, e2, c2v.x); c2v.y = fmaf(cAv, e2, c2v.y);
      c3v.x = fmaf(-cD, e3, c3v.x); c3v.y = fmaf(cAv, e3, c3v.y);
      dav[j0      ] = c0v;
      dav[j0 + 256] = c1v;
      dav[j0 + 512] = c2v;
      dav[j0 + 768] = c3v;

      A += cA.z;

      // UNCONDITIONAL re-read of window k+1 (always correct: identical
      // bytes to the prefetch when disjoint). Keeps lgkm counting linear.
      const float2 r0v = dav[j1      ];
      const float2 r1v = dav[j1 + 256];
      const float2 r2v = dav[j1 + 512];
      const float2 r3v = dav[j1 + 768];

      // speculative prefetch for k+2 (after iter-k writes -> fresh w.r.t.
      // all iterations <= k; iter k+1's select covers overlap with k+1)
      const int j2 = swz(cBnn.x + rbase, cBnn.y + cbase);
      const float2 s0 = dav[j2      ]; const float t0 = barr[j2      ];
      const float2 s1 = dav[j2 + 256]; const float t1 = barr[j2 + 256];
      const float2 s2 = dav[j2 + 512]; const float t2 = barr[j2 + 512];
      const float2 s3 = dav[j2 + 768]; const float t3 = barr[j2 + 768];

      // Uniform select: windows intersect iff |dr0|<16 && |dc0|<16 (wave-
      // uniform ints). readfirstlane -> scalar s_cbranch; the asm-volatile
      // arms keep SimplifyCFG from if-converting to cndmask (which would
      // consume the re-read registers on BOTH paths and force the wait).
      const int dr = cB.x - cBn.x;
      const int dc = cB.y - cBn.y;
      const int ovl = ((unsigned)(dr + 15) < 31u) & ((unsigned)(dc + 15) < 31u);
      if (__builtin_amdgcn_readfirstlane(ovl)) {
        asm volatile("" ::: );                 // keep a real branch
        c0v = r0v; c1v = r1v; c2v = r2v; c3v = r3v;   // waits re-read only
      } else {
        asm volatile("" ::: );                 // keep a real branch
        c0v = d0n; c1v = d1n; c2v = d2n; c3v = d3n;   // iteration-old: no wait
      }
      // b is immutable in phase 1 -> prefetch is always valid
      b0v = b0n; b1v = b1n; b2v = b2n; b3v = b3n;

      // rotate (deleted by copy-prop under unroll-2; no consume-at-issue)
      cA = cAn; cB = cBn; j0 = j1;
      cAn = cAnn; cBn = cBnn; j1 = j2;
      d0n = s0; d1n = s1; d2n = s2; d3n = s3;
      b0n = t0; b1n = t1; b2n = t2; b3n = t3;
    }
  }
  __syncthreads();                               // dav final; spfin ready

  // ---- epilogue (ALL 16 waves, own slab): barr <- w[]; ot partials ----
  {
    const float SP = spfin;
    float p_ot = 0.0f;
    #pragma unroll
    for (int l = 0; l < 4; ++l) {
      const int idx = swz(4 * v + l, L);
      const float2 cd = dav[idx];
      const float bb  = barr[idx];
      const float tt  = fmaf(bb, SP, -cd.y);     // 0.1*beta
      barr[idx] = tt + __logf(bb);               // w = 0.1*beta + lnb
      p_ot = fmaf(bb, 10.0f * tt, p_ot);
    }
    p_ot = waveSum(p_ot);
    if (L == 0) otred[v] = p_ot;
  }
  __syncthreads();                               // barr now holds w[]

  // ---- phase 2: windowed per-point wd, 4 points/pass interleaved (R12) ----
  float wdacc = 0.0f;
  for (int g = 0; g < 8; ++g) {
    float pe[4], pq[4];
    #pragma unroll
    for (int i = 0; i < 4; ++i) {
      const int p = 32 * v + 4 * g + i;
      const float2 pt = pts2[p];                 // LDS broadcast
      const float x = pt.x, y = pt.y;
      const int rn = (int)floorf((y - 4.0f) * 0.125f + 0.5f);
      const int cn = (int)floorf((x - 4.0f) * 0.125f + 0.5f);
      int r0 = rn - 7; r0 = r0 < 0 ? 0 : (r0 > R0MAX ? R0MAX : r0);
      int c0 = cn - 7; c0 = c0 < 0 ? 0 : (c0 > R0MAX ? R0MAX : c0);
      const int rl = r0 + rbase;
      const int cl = c0 + cbase;
      const int j0 = swz(rl, cl);

      const float dx  = x - (float)(8 * cl + 4);
      const float dxx = dx * dx;
      const float ty  = y - (float)(8 * rl + 4);
      float spe = 0.0f, spq = 0.0f;
      #pragma unroll
      for (int q = 0; q < 4; ++q) {
        const float wv = barr[j0 + 256 * q];
        const float dy = ty - (float)(32 * q);
        const float qq = fmaf(dy, dy, dxx);
        const float e  = __expf(fmaf(qq, -0.1f, wv));
        spe += e;
        spq = fmaf(e, qq, spq);
      }
      pe[i] = spe; pq[i] = spq;
    }
    // 8 interleaved DPP sum chains
    #pragma unroll
    for (int i = 0; i < 4; ++i) { pe[i] += dpp_mv<0x111>(pe[i], 0.0f); pq[i] += dpp_mv<0x111>(pq[i], 0.0f); }
    #pragma unroll
    for (int i = 0; i < 4; ++i) { pe[i] += dpp_mv<0x112>(pe[i], 0.0f); pq[i] += dpp_mv<0x112>(pq[i], 0.0f); }
    #pragma unroll
    for (int i = 0; i < 4; ++i) { pe[i] += dpp_mv<0x114>(pe[i], 0.0f); pq[i] += dpp_mv<0x114>(pq[i], 0.0f); }
    #pragma unroll
    for (int i = 0; i < 4; ++i) { pe[i] += dpp_mv<0x118>(pe[i], 0.0f); pq[i] += dpp_mv<0x118>(pq[i], 0.0f); }
    #pragma unroll
    for (int i = 0; i < 4; ++i) { pe[i] += dpp_mv<0x142>(pe[i], 0.0f); pq[i] += dpp_mv<0x142>(pq[i], 0.0f); }
    #pragma unroll
    for (int i = 0; i < 4; ++i) { pe[i] += dpp_mv<0x143>(pe[i], 0.0f); pq[i] += dpp_mv<0x143>(pq[i], 0.0f); }
    #pragma unroll
    for (int i = 0; i < 4; ++i) {
      const float PE = __int_as_float(__builtin_amdgcn_readlane(__float_as_int(pe[i]), 63));
      const float PQ = __int_as_float(__builtin_amdgcn_readlane(__float_as_int(pq[i]), 63));
      wdacc = fmaf(PQ, __builtin_amdgcn_rcpf(PE), wdacc);
    }
  }
  if (L == 0) wdred[v] = wdacc;
  __syncthreads();
  if (t == 0) {
    float wd = 0.0f, ot = 0.0f;
    #pragma unroll
    for (int i = 0; i < 16; ++i) { wd += wdred[i]; ot += otred[i]; }
    atomicAdd(&out[1], wd * (1.0f / 512.0f));
    atomicAdd(&out[2], ot);
    // out[0] (loss): analytically exact 0; memset provides it.
  }
}

extern "C" void kernel_launch(void* const* d_in, const int* in_sizes, int n_in,
                              void* d_out, int out_size, void* d_ws, size_t ws_size,
                              hipStream_t stream)
{
  (void)in_sizes; (void)n_in; (void)out_size; (void)d_ws; (void)ws_size;
  const float *normed = (const float *)d_in[0];
  const float *pts    = (const float *)d_in[2];
  float *out = (float *)d_out;

  hipMemsetAsync(out, 0, 3 * sizeof(float), stream);
  kern_fused<<<dim3(NSAMP), dim3(1024), 0, stream>>>(normed, pts, out);
}

// Round 3
// 92.979 us; speedup vs baseline: 1.0533x; 1.0385x over previous
//
#include <hip/hip_runtime.h>
#include <math.h>

// Problem constants (from reference)
#define NSAMP 16
#define NPTS  512
#define MDIM  4096     // 64*64 grid
#define NIT   100

// 16x16 window (rows rn-7..rn+8, cols cn-7..cn+8), 4 cells/lane for a wave.
// Support analysis (R4-R12-validated): first-visit pits displace the softmax
// mode ~3 cells; rim + mass tail needs +-6 cells -> 16x16 minimum safe.
#define R0MAX 48

// Max iterations executed in parallel per batch (waves 0..MAXB-1).
#define MAXB 4

// No-max softmax safety (R12-validated): z = v - 0.1*d^2 < 0 always and
// S >= e^-28 -> unshifted __expf neither overflows nor underflows S.

// parity swizzle: odd rows XOR col by 16 -> ~2 lanes/bank (R7: 75k -> 2k).
__device__ __forceinline__ int swz(int r, int c) {
  return r * 64 + (c ^ ((r & 1) << 4));
}

// windows (16x16 at r0,c0) disjoint iff |dr0|>=16 || |dc0|>=16
__device__ __forceinline__ int wdisj(int2 a, int2 b) {
  int dr = a.x - b.x; if (dr < 0) dr = -dr;
  int dc = a.y - b.y; if (dc < 0) dc = -dc;
  return (dr >= 16) | (dc >= 16);
}

// ---------------- Threefry-2x32 (JAX-exact, partitionable path; R0-verified)
__device__ __forceinline__ void tf2x32(unsigned k0, unsigned k1,
                                       unsigned c0, unsigned c1,
                                       unsigned &o0, unsigned &o1)
{
  unsigned ks2 = k0 ^ k1 ^ 0x1BD11BDAu;
  unsigned x0 = c0 + k0, x1 = c1 + k1;
#define ROT(r) x0 += x1; x1 = (x1 << (r)) | (x1 >> (32 - (r))); x1 ^= x0;
#define G0 ROT(13) ROT(15) ROT(26) ROT(6)
#define G1 ROT(17) ROT(29) ROT(16) ROT(24)
  G0 x0 += k1;  x1 += ks2 + 1u;
  G1 x0 += ks2; x1 += k0  + 2u;
  G0 x0 += k0;  x1 += k1  + 3u;
  G1 x0 += k1;  x1 += ks2 + 4u;
  G0 x0 += ks2; x1 += k0  + 5u;
#undef G0
#undef G1
#undef ROT
  o0 = x0; o1 = x1;
}

__device__ __forceinline__ int rand_idx(int f)
{
  unsigned ka, kb, w0, w1;
  tf2x32(0u, 1u, 0u, 1u, ka, kb);            // split(key(1))[1] — folded
  tf2x32(ka, kb, 0u, (unsigned)f, w0, w1);   // random_bits elem f
  return (int)((w0 ^ w1) & 511u);
}

// ---------------- wave64 sum via DPP (R1-R12-verified pattern) --------------
template<int CTRL>
__device__ __forceinline__ float dpp_mv(float v, float id)
{
  return __int_as_float(__builtin_amdgcn_update_dpp(
      __float_as_int(id), __float_as_int(v), CTRL, 0xF, 0xF, false));
}

__device__ __forceinline__ float waveSum(float v)
{
  v += dpp_mv<0x111>(v, 0.0f);
  v += dpp_mv<0x112>(v, 0.0f);
  v += dpp_mv<0x114>(v, 0.0f);
  v += dpp_mv<0x118>(v, 0.0f);
  v += dpp_mv<0x142>(v, 0.0f);
  v += dpp_mv<0x143>(v, 0.0f);
  return __int_as_float(__builtin_amdgcn_readlane(__float_as_int(v), 63));
}

// ---------------- Fused kernel: batched scan + rows (16 waves) --------------
// Phase 1 (R6-R12-validated algebra): v = 0.1*cur + lnb = D + b*A lazily;
// avacc = sum(Pk*khi), Pk = step1*(101-k)/100; beta = 10*(b*SP - avacc);
// w = 0.1*beta + lnb. loss: analytically 0.
//
// R16: BATCHED COMMUTING ITERATIONS. R14/R15 showed the LDS round-trip is
// NOT the phase-1 bottleneck (a no-wait fast path saved nothing): the scan
// is bound by single-wave issue rate + exposed dependent latency. But
// consecutive iterations with pairwise-disjoint windows commute BIT-EXACTLY:
// updates land in disjoint dav cells; each one's reads are untouched by the
// others; A is a pure precomputable float prefix (same add order). A greedy
// schedule groups consecutive runs (<=MAXB, pairwise disjoint; E[batch]~2.2)
// and waves 0..size-1 execute one iteration each in parallel, barrier between
// batches -> ~45 serial steps instead of 100. Per-wave body identical to the
// serial version (same lane mapping, same fma/waveSum trees) -> results
// bit-identical; absmax must stay exactly 2.533197e-06.
__global__ __launch_bounds__(1024) void kern_fused(
    const float *__restrict__ normed, const float *__restrict__ pts,
    float *__restrict__ out)
{
  const int s = blockIdx.x;
  const int t = threadIdx.x;
  const int v = t >> 6;            // wave 0..15
  const int L = t & 63;

  __shared__ float2 dav[MDIM];     // 32 KB: (D, avacc), swizzled
  __shared__ float  barr[MDIM];    // 16 KB: b, becomes w[] after epilogue
  __shared__ float2 pts2[NPTS];    // 4 KB
  __shared__ float4 cstA[NIT + 4]; // (ux, uy, step1, Pk) per iter
  __shared__ int2   cstB[NIT + 4]; // (r0, c0) per iter
  __shared__ float  Aarr[NIT];     // exact exclusive prefix of 0.1*lr/sqrt(k)
  __shared__ int    lenb[NIT];     // greedy run length if a batch starts at k
  __shared__ int    bstart_s[NIT]; // batch -> first iteration
  __shared__ int    bsize_s[NIT];  // batch -> size (1..MAXB)
  __shared__ int    nbat_s;
  __shared__ float  spfin;         // exact sum of Pk, k ascending
  __shared__ float  wdred[16], otred[16];

  // ---- init (all 16 waves; wave v owns grid rows 4v..4v+3) ----
  #pragma unroll
  for (int l = 0; l < 4; ++l) {
    const int r = 4 * v + l;
    const float bv = normed[s * MDIM + r * 64 + L];
    const int idx = swz(r, L);
    dav[idx]  = make_float2(__logf(bv), 0.0f);   // v0 = lnb
    barr[idx] = bv;
  }
  if (t < NPTS) pts2[t] = ((const float2 *)pts)[s * NPTS + t];
  // per-iteration constants (bit-identical formulas, hoisted; R8-validated)
  if (t < NIT + 4) {
    const int kk = t < NIT ? t : (NIT - 1);
    const int idx = rand_idx(s * NIT + kk);
    const float2 p = ((const float2 *)pts)[s * NPTS + idx];
    const int rn = (int)floorf((p.y - 4.0f) * 0.125f + 0.5f);
    const int cn = (int)floorf((p.x - 4.0f) * 0.125f + 0.5f);
    int r0 = rn - 7; r0 = r0 < 0 ? 0 : (r0 > R0MAX ? R0MAX : r0);
    int c0 = cn - 7; c0 = c0 < 0 ? 0 : (c0 > R0MAX ? R0MAX : c0);
    const float kf    = (float)(kk + 1);
    const float step1 = 512.0f * __builtin_amdgcn_rsqf(kf);   // 0.1*lr/sqrt(k)
    const float Pk    = step1 * (0.01f * (101.0f - kf));
    cstA[t] = make_float4(p.x - (float)(8 * c0 + 4),
                          p.y - (float)(8 * r0 + 4), step1, Pk);
    cstB[t] = make_int2(r0, c0);
  }
  __syncthreads();

  // ---- schedule step A (parallel): greedy run length starting at k ----
  if (t < NIT) {
    const int2 w0 = cstB[t];
    int e1 = 0, e2 = 0, e3 = 0;
    if (t + 1 < NIT) {
      const int2 w1 = cstB[t + 1];
      e1 = wdisj(w0, w1);
      if (e1 && t + 2 < NIT) {
        const int2 w2 = cstB[t + 2];
        e2 = wdisj(w0, w2) & wdisj(w1, w2);
        if (e2 && t + 3 < NIT) {
          const int2 w3 = cstB[t + 3];
          e3 = wdisj(w0, w3) & wdisj(w1, w3) & wdisj(w2, w3);
        }
      }
    }
    lenb[t] = 1 + e1 + e2 + e3;     // 1..MAXB
  }
  __syncthreads();

  // ---- schedule step B: chain-follow (t0) || exact prefixes (t64) ----
  if (t == 0) {
    int i = 0, b = 0;
    while (i < NIT) {
      bstart_s[b] = i;
      const int Lb = lenb[i];
      bsize_s[b] = Lb;
      i += Lb;
      ++b;
    }
    nbat_s = b;
  } else if (t == 64) {
    // identical add order to the serial loop's A += cA.z / SP += cA.w
    float A = 0.0f, SPa = 0.0f;
    for (int k = 0; k < NIT; ++k) {
      Aarr[k] = A;
      A   += cstA[k].z;
      SPa += cstA[k].w;
    }
    spfin = SPa;
  }
  __syncthreads();

  const int rbase = L >> 4;        // 0..3 (window row within quad)
  const int cbase = L & 15;        // window col
  const float fc8 = (float)(8 * cbase);
  const float fr8 = (float)(8 * rbase);

  // ---- phase 1: batched ASGD scan; batch b = waves 0..size-1 in parallel --
  {
    const int nb = nbat_s;
    int   msize = bsize_s[0];
    int   kme   = bstart_s[0] + (v < msize ? v : 0);
    float4 cA = cstA[kme];
    int2   cB = cstB[kme];
    float  Ak = Aarr[kme];

    for (int b = 0; b < nb; ++b) {
      // prefetch next batch's meta + constants (immutable LDS; consumed
      // only after the barrier + a full compute -> latency fully hidden)
      const int bn  = (b + 1 < nb) ? b + 1 : b;
      const int sz2 = bsize_s[bn];
      const int kn  = bstart_s[bn] + (v < sz2 ? v : 0);
      const float4 cAn = cstA[kn];
      const int2   cBn = cstB[kn];
      const float  An  = Aarr[kn];

      if (v < msize) {
        const int j0 = swz(cB.x + rbase, cB.y + cbase);
        float2 c0v = dav[j0      ]; const float b0v = barr[j0      ];
        float2 c1v = dav[j0 + 256]; const float b1v = barr[j0 + 256];
        float2 c2v = dav[j0 + 512]; const float b2v = barr[j0 + 512];
        float2 c3v = dav[j0 + 768]; const float b3v = barr[j0 + 768];

        const float dx  = cA.x - fc8;       // x - (8*(c0+cbase)+4)
        const float dxx = dx * dx;
        const float ty  = cA.y - fr8;       // dy_q = ty - 32q
        // unshifted exp: z < 0 always (R12-validated)
        const float e0 = __expf(fmaf(fmaf(ty,          ty,          dxx), -0.1f, fmaf(b0v, Ak, c0v.x)));
        const float e1 = __expf(fmaf(fmaf(ty - 32.0f, ty - 32.0f, dxx), -0.1f, fmaf(b1v, Ak, c1v.x)));
        const float e2 = __expf(fmaf(fmaf(ty - 64.0f, ty - 64.0f, dxx), -0.1f, fmaf(b2v, Ak, c2v.x)));
        const float e3 = __expf(fmaf(fmaf(ty - 96.0f, ty - 96.0f, dxx), -0.1f, fmaf(b3v, Ak, c3v.x)));

        const float S    = waveSum((e0 + e1) + (e2 + e3));   // > 0
        const float invS = __builtin_amdgcn_rcpf(S);
        const float cD = cA.z * invS, cAv = cA.w * invS;

        c0v.x = fmaf(-cD, e0, c0v.x); c0v.y = fmaf(cAv, e0, c0v.y);
        c1v.x = fmaf(-cD, e1, c1v.x); c1v.y = fmaf(cAv, e1, c1v.y);
        c2v.x = fmaf(-cD, e2, c2v.x); c2v.y = fmaf(cAv, e2, c2v.y);
        c3v.x = fmaf(-cD, e3, c3v.x); c3v.y = fmaf(cAv, e3, c3v.y);
        dav[j0      ] = c0v;
        dav[j0 + 256] = c1v;
        dav[j0 + 512] = c2v;
        dav[j0 + 768] = c3v;
      }
      __syncthreads();               // batch writes visible to next batch
      msize = sz2; cA = cAn; cB = cBn; Ak = An;
    }
  }
  // (last in-loop barrier: dav final; spfin long since ready)

  // ---- epilogue (ALL 16 waves, own slab): barr <- w[]; ot partials ----
  {
    const float SP = spfin;
    float p_ot = 0.0f;
    #pragma unroll
    for (int l = 0; l < 4; ++l) {
      const int idx = swz(4 * v + l, L);
      const float2 cd = dav[idx];
      const float bb  = barr[idx];
      const float tt  = fmaf(bb, SP, -cd.y);     // 0.1*beta
      barr[idx] = tt + __logf(bb);               // w = 0.1*beta + lnb
      p_ot = fmaf(bb, 10.0f * tt, p_ot);
    }
    p_ot = waveSum(p_ot);
    if (L == 0) otred[v] = p_ot;
  }
  __syncthreads();                               // barr now holds w[]

  // ---- phase 2: windowed per-point wd, 4 points/pass interleaved (R12) ----
  float wdacc = 0.0f;
  for (int g = 0; g < 8; ++g) {
    float pe[4], pq[4];
    #pragma unroll
    for (int i = 0; i < 4; ++i) {
      const int p = 32 * v + 4 * g + i;
      const float2 pt = pts2[p];                 // LDS broadcast
      const float x = pt.x, y = pt.y;
      const int rn = (int)floorf((y - 4.0f) * 0.125f + 0.5f);
      const int cn = (int)floorf((x - 4.0f) * 0.125f + 0.5f);
      int r0 = rn - 7; r0 = r0 < 0 ? 0 : (r0 > R0MAX ? R0MAX : r0);
      int c0 = cn - 7; c0 = c0 < 0 ? 0 : (c0 > R0MAX ? R0MAX : c0);
      const int rl = r0 + rbase;
      const int cl = c0 + cbase;
      const int j0 = swz(rl, cl);

      const float dx  = x - (float)(8 * cl + 4);
      const float dxx = dx * dx;
      const float ty  = y - (float)(8 * rl + 4);
      float spe = 0.0f, spq = 0.0f;
      #pragma unroll
      for (int q = 0; q < 4; ++q) {
        const float wv = barr[j0 + 256 * q];
        const float dy = ty - (float)(32 * q);
        const float qq = fmaf(dy, dy, dxx);
        const float e  = __expf(fmaf(qq, -0.1f, wv));
        spe += e;
        spq = fmaf(e, qq, spq);
      }
      pe[i] = spe; pq[i] = spq;
    }
    // 8 interleaved DPP sum chains
    #pragma unroll
    for (int i = 0; i < 4; ++i) { pe[i] += dpp_mv<0x111>(pe[i], 0.0f); pq[i] += dpp_mv<0x111>(pq[i], 0.0f); }
    #pragma unroll
    for (int i = 0; i < 4; ++i) { pe[i] += dpp_mv<0x112>(pe[i], 0.0f); pq[i] += dpp_mv<0x112>(pq[i], 0.0f); }
    #pragma unroll
    for (int i = 0; i < 4; ++i) { pe[i] += dpp_mv<0x114>(pe[i], 0.0f); pq[i] += dpp_mv<0x114>(pq[i], 0.0f); }
    #pragma unroll
    for (int i = 0; i < 4; ++i) { pe[i] += dpp_mv<0x118>(pe[i], 0.0f); pq[i] += dpp_mv<0x118>(pq[i], 0.0f); }
    #pragma unroll
    for (int i = 0; i < 4; ++i) { pe[i] += dpp_mv<0x142>(pe[i], 0.0f); pq[i] += dpp_mv<0x142>(pq[i], 0.0f); }
    #pragma unroll
    for (int i = 0; i < 4; ++i) { pe[i] += dpp_mv<0x143>(pe[i], 0.0f); pq[i] += dpp_mv<0x143>(pq[i], 0.0f); }
    #pragma unroll
    for (int i = 0; i < 4; ++i) {
      const float PE = __int_as_float(__builtin_amdgcn_readlane(__float_as_int(pe[i]), 63));
      const float PQ = __int_as_float(__builtin_amdgcn_readlane(__float_as_int(pq[i]), 63));
      wdacc = fmaf(PQ, __builtin_amdgcn_rcpf(PE), wdacc);
    }
  }
  if (L == 0) wdred[v] = wdacc;
  __syncthreads();
  if (t == 0) {
    float wd = 0.0f, ot = 0.0f;
    #pragma unroll
    for (int i = 0; i < 16; ++i) { wd += wdred[i]; ot += otred[i]; }
    atomicAdd(&out[1], wd * (1.0f / 512.0f));
    atomicAdd(&out[2], ot);
    // out[0] (loss): analytically exact 0; memset provides it.
  }
}

extern "C" void kernel_launch(void* const* d_in, const int* in_sizes, int n_in,
                              void* d_out, int out_size, void* d_ws, size_t ws_size,
                              hipStream_t stream)
{
  (void)in_sizes; (void)n_in; (void)out_size; (void)d_ws; (void)ws_size;
  const float *normed = (const float *)d_in[0];
  const float *pts    = (const float *)d_in[2];
  float *out = (float *)d_out;

  hipMemsetAsync(out, 0, 3 * sizeof(float), stream);
  kern_fused<<<dim3(NSAMP), dim3(1024), 0, stream>>>(normed, pts, out);
}

// Round 4
// 84.297 us; speedup vs baseline: 1.1617x; 1.1030x over previous
//
#include <hip/hip_runtime.h>
#include <math.h>

// Problem constants (from reference)
#define NSAMP 16
#define NPTS  512
#define MDIM  4096     // 64*64 grid
#define NIT   100

// 16x16 window (rows rn-7..rn+8, cols cn-7..cn+8), 4 cells/lane for a wave.
// Support analysis (R4-R12-validated): first-visit pits displace the softmax
// mode ~3 cells; rim + mass tail needs +-6 cells -> 16x16 minimum safe.
#define R0MAX 48

// No-max softmax safety (R12-validated): z = v - 0.1*d^2 < 0 always and
// S >= e^-28 -> unshifted __expf neither overflows nor underflows S.

// parity swizzle: odd rows XOR col by 16 -> ~2 lanes/bank (R7: 75k -> 2k).
__device__ __forceinline__ int swz(int r, int c) {
  return r * 64 + (c ^ ((r & 1) << 4));
}

// ---------------- Threefry-2x32 (JAX-exact, partitionable path; R0-verified)
__device__ __forceinline__ void tf2x32(unsigned k0, unsigned k1,
                                       unsigned c0, unsigned c1,
                                       unsigned &o0, unsigned &o1)
{
  unsigned ks2 = k0 ^ k1 ^ 0x1BD11BDAu;
  unsigned x0 = c0 + k0, x1 = c1 + k1;
#define ROT(r) x0 += x1; x1 = (x1 << (r)) | (x1 >> (32 - (r))); x1 ^= x0;
#define G0 ROT(13) ROT(15) ROT(26) ROT(6)
#define G1 ROT(17) ROT(29) ROT(16) ROT(24)
  G0 x0 += k1;  x1 += ks2 + 1u;
  G1 x0 += ks2; x1 += k0  + 2u;
  G0 x0 += k0;  x1 += k1  + 3u;
  G1 x0 += k1;  x1 += ks2 + 4u;
  G0 x0 += ks2; x1 += k0  + 5u;
#undef G0
#undef G1
#undef ROT
  o0 = x0; o1 = x1;
}

__device__ __forceinline__ int rand_idx(int f)
{
  unsigned ka, kb, w0, w1;
  tf2x32(0u, 1u, 0u, 1u, ka, kb);            // split(key(1))[1] — folded
  tf2x32(ka, kb, 0u, (unsigned)f, w0, w1);   // random_bits elem f
  return (int)((w0 ^ w1) & 511u);
}

// ---------------- wave64 sum via DPP (R1-R12-verified pattern) --------------
template<int CTRL>
__device__ __forceinline__ float dpp_mv(float v, float id)
{
  return __int_as_float(__builtin_amdgcn_update_dpp(
      __float_as_int(id), __float_as_int(v), CTRL, 0xF, 0xF, false));
}

__device__ __forceinline__ float waveSum(float v)
{
  v += dpp_mv<0x111>(v, 0.0f);
  v += dpp_mv<0x112>(v, 0.0f);
  v += dpp_mv<0x114>(v, 0.0f);
  v += dpp_mv<0x118>(v, 0.0f);
  v += dpp_mv<0x142>(v, 0.0f);
  v += dpp_mv<0x143>(v, 0.0f);
  return __int_as_float(__builtin_amdgcn_readlane(__float_as_int(v), 63));
}

// ---------------- Kernel 1: scan (R13 serial phase 1) + epilogue -> w[] -----
// R17: phases split across dispatches. R15/R16 proved phase 1 is issue-bound
// (~10-16 us) and already near its single-wave floor; the missing time was
// phase 2 running 16 waves on ONE CU per sample (per-SIMD issue demand
// ~25k cy ~ 10-14 us wall on 16 of 256 CUs). kern_scan keeps the R13-exact
// phase-1 loop (bit-identical), writes w[] to global workspace; kern_wd
// spreads phase 2 over 128 blocks (8 slices/sample). Per-point math is
// bit-identical; only the wd summation tree regroups (128 atomics vs 16).
__global__ __launch_bounds__(1024) void kern_scan(
    const float *__restrict__ normed, const float *__restrict__ pts,
    float *__restrict__ out, float *__restrict__ wglob)
{
  const int s = blockIdx.x;
  const int t = threadIdx.x;
  const int v = t >> 6;            // wave 0..15
  const int L = t & 63;

  __shared__ float2 dav[MDIM];     // 32 KB: (D, avacc), swizzled
  __shared__ float  barr[MDIM];    // 16 KB: b (phase-1 softmax weights)
  __shared__ float4 cstA[NIT + 4]; // (ux, uy, step1, Pk) per iter
  __shared__ int2   cstB[NIT + 4]; // (r0, c0) per iter
  __shared__ float  spfin;         // exact sum of Pk, k ascending
  __shared__ float  otred[16];

  // ---- init (all 16 waves; wave v owns grid rows 4v..4v+3) ----
  #pragma unroll
  for (int l = 0; l < 4; ++l) {
    const int r = 4 * v + l;
    const float bv = normed[s * MDIM + r * 64 + L];
    const int idx = swz(r, L);
    dav[idx]  = make_float2(__logf(bv), 0.0f);   // v0 = lnb
    barr[idx] = bv;
  }
  // per-iteration constants (bit-identical formulas, hoisted; R8-validated)
  if (t < NIT + 4) {
    const int kk = t < NIT ? t : (NIT - 1);
    const int idx = rand_idx(s * NIT + kk);
    const float2 p = ((const float2 *)pts)[s * NPTS + idx];
    const int rn = (int)floorf((p.y - 4.0f) * 0.125f + 0.5f);
    const int cn = (int)floorf((p.x - 4.0f) * 0.125f + 0.5f);
    int r0 = rn - 7; r0 = r0 < 0 ? 0 : (r0 > R0MAX ? R0MAX : r0);
    int c0 = cn - 7; c0 = c0 < 0 ? 0 : (c0 > R0MAX ? R0MAX : c0);
    const float kf    = (float)(kk + 1);
    const float step1 = 512.0f * __builtin_amdgcn_rsqf(kf);   // 0.1*lr/sqrt(k)
    const float Pk    = step1 * (0.01f * (101.0f - kf));
    cstA[t] = make_float4(p.x - (float)(8 * c0 + 4),
                          p.y - (float)(8 * r0 + 4), step1, Pk);
    cstB[t] = make_int2(r0, c0);
  }
  __syncthreads();

  const int rbase = L >> 4;        // 0..3 (window row within quad)
  const int cbase = L & 15;        // window col
  const float fc8 = (float)(8 * cbase);
  const float fr8 = (float)(8 * rbase);

  // ---- phase 1: 100-iter ASGD scan, wave 0 only (R13-exact body) ----
  // (wave 1 lane 0 concurrently builds spfin with the identical add order)
  if (t == 64) {
    float SPa = 0.0f;
    for (int k = 0; k < NIT; ++k) SPa += cstA[k].w;
    spfin = SPa;
  }
  if (v == 0) {
    float A = 0.0f;
    // preload iter 0: constants + state (R8 pipelined pattern)
    float4 cA = cstA[0];
    int2   cB = cstB[0];
    int j0 = swz(cB.x + rbase, cB.y + cbase);
    float2 c0v = dav[j0      ]; float b0v = barr[j0      ];
    float2 c1v = dav[j0 + 256]; float b1v = barr[j0 + 256];
    float2 c2v = dav[j0 + 512]; float b2v = barr[j0 + 512];
    float2 c3v = dav[j0 + 768]; float b3v = barr[j0 + 768];

    for (int k = 0; k < NIT; ++k) {
      // prefetch next-iter constants (independent; latency hidden under chain)
      const float4 cAn = cstA[k + 1];
      const int2   cBn = cstB[k + 1];

      const float dx  = cA.x - fc8;       // x - (8*(c0+cbase)+4)
      const float dxx = dx * dx;
      const float ty  = cA.y - fr8;       // dy_q = ty - 32q
      // unshifted exp: z < 0 always (R12-validated) -> no max reduction
      const float e0 = __expf(fmaf(fmaf(ty,          ty,          dxx), -0.1f, fmaf(b0v, A, c0v.x)));
      const float e1 = __expf(fmaf(fmaf(ty - 32.0f, ty - 32.0f, dxx), -0.1f, fmaf(b1v, A, c1v.x)));
      const float e2 = __expf(fmaf(fmaf(ty - 64.0f, ty - 64.0f, dxx), -0.1f, fmaf(b2v, A, c2v.x)));
      const float e3 = __expf(fmaf(fmaf(ty - 96.0f, ty - 96.0f, dxx), -0.1f, fmaf(b3v, A, c3v.x)));

      const float S    = waveSum((e0 + e1) + (e2 + e3));   // > 0
      const float invS = __builtin_amdgcn_rcpf(S);
      const float cD = cA.z * invS, cAv = cA.w * invS;

      c0v.x = fmaf(-cD, e0, c0v.x); c0v.y = fmaf(cAv, e0, c0v.y);
      c1v.x = fmaf(-cD, e1, c1v.x); c1v.y = fmaf(cAv, e1, c1v.y);
      c2v.x = fmaf(-cD, e2, c2v.x); c2v.y = fmaf(cAv, e2, c2v.y);
      c3v.x = fmaf(-cD, e3, c3v.x); c3v.y = fmaf(cAv, e3, c3v.y);
      dav[j0      ] = c0v;
      dav[j0 + 256] = c1v;
      dav[j0 + 512] = c2v;
      dav[j0 + 768] = c3v;

      A += cA.z;

      // rotate + issue next-iter state reads AFTER the writes (same-wave DS
      // ordering guarantees RAW; latency overlaps loop-back + z-prep)
      cA = cAn; cB = cBn;
      j0 = swz(cB.x + rbase, cB.y + cbase);
      c0v = dav[j0      ]; b0v = barr[j0      ];
      c1v = dav[j0 + 256]; b1v = barr[j0 + 256];
      c2v = dav[j0 + 512]; b2v = barr[j0 + 512];
      c3v = dav[j0 + 768]; b3v = barr[j0 + 768];
    }
  }
  __syncthreads();                               // dav final; spfin ready

  // ---- epilogue (ALL 16 waves, own slab): w[] -> global; ot partials ----
  {
    const float SP = spfin;
    float p_ot = 0.0f;
    #pragma unroll
    for (int l = 0; l < 4; ++l) {
      const int r   = 4 * v + l;
      const int idx = swz(r, L);
      const float2 cd = dav[idx];
      const float bb  = barr[idx];
      const float tt  = fmaf(bb, SP, -cd.y);     // 0.1*beta
      wglob[s * MDIM + r * 64 + L] = tt + __logf(bb);  // w = 0.1*beta + lnb
      p_ot = fmaf(bb, 10.0f * tt, p_ot);
    }
    p_ot = waveSum(p_ot);
    if (L == 0) otred[v] = p_ot;
  }
  __syncthreads();
  if (t == 0) {
    float ot = 0.0f;
    #pragma unroll
    for (int i = 0; i < 16; ++i) ot += otred[i];
    atomicAdd(&out[2], ot);
    // out[0] (loss): analytically exact 0; memset provides it.
  }
}

// ---------------- Kernel 2: windowed per-point wd, 8 slice-blocks/sample ----
// Block b: sample s = b>>3, slice q = b&7 (points 64q..64q+63). 16 waves,
// 4 points each (one interleaved group — identical per-point math to R12's
// phase 2; only the cross-point summation tree regroups).
__global__ __launch_bounds__(1024) void kern_wd(
    const float *__restrict__ pts, const float *__restrict__ wglob,
    float *__restrict__ out)
{
  const int s = blockIdx.x >> 3;
  const int q = blockIdx.x & 7;
  const int t = threadIdx.x;
  const int v = t >> 6;            // wave 0..15
  const int L = t & 63;

  __shared__ float  wlds[MDIM];    // 16 KB: w[], swizzled as in kern_scan
  __shared__ float2 pts2[64];      // this slice's points
  __shared__ float  wdred[16];

  // stage w with the same parity swizzle so window reads are conflict-free
  #pragma unroll
  for (int l = 0; l < 4; ++l) {
    const int r = 4 * v + l;
    wlds[swz(r, L)] = wglob[s * MDIM + r * 64 + L];
  }
  if (t < 64) pts2[t] = ((const float2 *)pts)[s * NPTS + 64 * q + t];
  __syncthreads();

  const int rbase = L >> 4;        // 0..3 (window row within quad)
  const int cbase = L & 15;        // window col

  float pe[4], pq[4];
  #pragma unroll
  for (int i = 0; i < 4; ++i) {
    const int p = 4 * v + i;                   // point within slice
    const float2 pt = pts2[p];                 // LDS broadcast
    const float x = pt.x, y = pt.y;
    const int rn = (int)floorf((y - 4.0f) * 0.125f + 0.5f);
    const int cn = (int)floorf((x - 4.0f) * 0.125f + 0.5f);
    int r0 = rn - 7; r0 = r0 < 0 ? 0 : (r0 > R0MAX ? R0MAX : r0);
    int c0 = cn - 7; c0 = c0 < 0 ? 0 : (c0 > R0MAX ? R0MAX : c0);
    const int rl = r0 + rbase;
    const int cl = c0 + cbase;
    const int j0 = swz(rl, cl);

    const float dx  = x - (float)(8 * cl + 4);
    const float dxx = dx * dx;
    const float ty  = y - (float)(8 * rl + 4);
    float spe = 0.0f, spq = 0.0f;
    #pragma unroll
    for (int qq4 = 0; qq4 < 4; ++qq4) {
      const float wv = wlds[j0 + 256 * qq4];
      const float dy = ty - (float)(32 * qq4);
      const float qq = fmaf(dy, dy, dxx);
      const float e  = __expf(fmaf(qq, -0.1f, wv));
      spe += e;
      spq = fmaf(e, qq, spq);
    }
    pe[i] = spe; pq[i] = spq;
  }
  // 8 interleaved DPP sum chains
  #pragma unroll
  for (int i = 0; i < 4; ++i) { pe[i] += dpp_mv<0x111>(pe[i], 0.0f); pq[i] += dpp_mv<0x111>(pq[i], 0.0f); }
  #pragma unroll
  for (int i = 0; i < 4; ++i) { pe[i] += dpp_mv<0x112>(pe[i], 0.0f); pq[i] += dpp_mv<0x112>(pq[i], 0.0f); }
  #pragma unroll
  for (int i = 0; i < 4; ++i) { pe[i] += dpp_mv<0x114>(pe[i], 0.0f); pq[i] += dpp_mv<0x114>(pq[i], 0.0f); }
  #pragma unroll
  for (int i = 0; i < 4; ++i) { pe[i] += dpp_mv<0x118>(pe[i], 0.0f); pq[i] += dpp_mv<0x118>(pq[i], 0.0f); }
  #pragma unroll
  for (int i = 0; i < 4; ++i) { pe[i] += dpp_mv<0x142>(pe[i], 0.0f); pq[i] += dpp_mv<0x142>(pq[i], 0.0f); }
  #pragma unroll
  for (int i = 0; i < 4; ++i) { pe[i] += dpp_mv<0x143>(pe[i], 0.0f); pq[i] += dpp_mv<0x143>(pq[i], 0.0f); }

  float wdacc = 0.0f;
  #pragma unroll
  for (int i = 0; i < 4; ++i) {
    const float PE = __int_as_float(__builtin_amdgcn_readlane(__float_as_int(pe[i]), 63));
    const float PQ = __int_as_float(__builtin_amdgcn_readlane(__float_as_int(pq[i]), 63));
    wdacc = fmaf(PQ, __builtin_amdgcn_rcpf(PE), wdacc);
  }
  if (L == 0) wdred[v] = wdacc;
  __syncthreads();
  if (t == 0) {
    float wd = 0.0f;
    #pragma unroll
    for (int i = 0; i < 16; ++i) wd += wdred[i];
    atomicAdd(&out[1], wd * (1.0f / 512.0f));
  }
}

extern "C" void kernel_launch(void* const* d_in, const int* in_sizes, int n_in,
                              void* d_out, int out_size, void* d_ws, size_t ws_size,
                              hipStream_t stream)
{
  (void)in_sizes; (void)n_in; (void)out_size; (void)ws_size;
  const float *normed = (const float *)d_in[0];
  const float *pts    = (const float *)d_in[2];
  float *out   = (float *)d_out;
  float *wglob = (float *)d_ws;    // 16 * 4096 * 4 B = 256 KB of workspace

  hipMemsetAsync(out, 0, 3 * sizeof(float), stream);
  kern_scan<<<dim3(NSAMP),     dim3(1024), 0, stream>>>(normed, pts, out, wglob);
  kern_wd  <<<dim3(NSAMP * 8), dim3(1024), 0, stream>>>(pts, wglob, out);
}